// Round 4
// baseline (241.163 us; speedup 1.0000x reference)
//
#include <hip/hip_runtime.h>
#include <cstdint>
#include <cstddef>

#define BS      64
#define NPRED   25200
#define KTOP    512
#define MAXDET  300
#define NBINS   4096
#define CAP     1024
#define NTHR    1024
#define CONF_T  0.25f
#define IOU_T   0.45f
#define MAXWH   7680.0f
#define MSTRIDE 17

__device__ __forceinline__ unsigned long long shflx64(unsigned long long v, int m) {
  unsigned lo = __shfl_xor((unsigned)(v & 0xffffffffull), m, 64);
  unsigned hi = __shfl_xor((unsigned)(v >> 32), m, 64);
  return (((unsigned long long)hi) << 32) | lo;
}

__device__ __forceinline__ float scoreOf(const float4& q) {
  return fmaxf(q.x * q.y, fmaxf(q.x * q.z, q.x * q.w));
}

// ---- K1: score + per-image histogram via global atomics (full-grid) ----
__global__ __launch_bounds__(256) void score_hist_k(const float* __restrict__ pred,
                                                    unsigned int* __restrict__ ghist) {
  const int img = blockIdx.y;
  const int e = blockIdx.x * 256 + threadIdx.x;
  if (e >= NPRED) return;
  const float4 q = *reinterpret_cast<const float4*>(pred + ((size_t)img * NPRED + e) * 8 + 4);
  float m = scoreOf(q);
  int b = (int)(m * (float)NBINS);
  b = min(max(b, 0), NBINS - 1);
  atomicAdd(&ghist[(img << 12) + b], 1u);
}

// ---- K2: per-image top-K select/sort + NMS + pack ----
template<bool GHIST>
__global__ __launch_bounds__(NTHR) void nms_k(const float* __restrict__ pred,
                                              const unsigned int* __restrict__ ghist,
                                              float* __restrict__ out) {
  __shared__ unsigned long long keysL[CAP];                    // 8 KB
  __shared__ __align__(16) unsigned int maskA[KTOP * MSTRIDE]; // 34.8 KB (hist overlay in !GHIST)
  __shared__ float ox0[KTOP], oy0[KTOP], ox1[KTOP], oy1[KTOP], areaL[KTOP];
  __shared__ float bx0[KTOP], bx1[KTOP], bx2[KTOP], bx3[KTOP];
  __shared__ float svL[KTOP]; __shared__ int siL[KTOP]; __shared__ int cidL[KTOP];
  __shared__ unsigned int supW[16];
  __shared__ unsigned int wtot[16];
  __shared__ int woff[8];
  __shared__ int cutoff_s, cnt_s, nvalid_s;

  const int tid = threadIdx.x;
  const int lane = tid & 63;
  const int wid = tid >> 6;
  const int img = blockIdx.x;
  const float* __restrict__ base = pred + (size_t)img * (NPRED * 8);

  if (tid == 0) cnt_s = 0;

  // ---- phase A: histogram (load prebuilt, or build locally) -> regs h0..h3 ----
  unsigned h0, h1, h2, h3;
  if (GHIST) {
    const uint4 h = *reinterpret_cast<const uint4*>(ghist + ((size_t)img << 12) + (tid << 2));
    h0 = h.x; h1 = h.y; h2 = h.z; h3 = h.w;
  } else {
    unsigned int* hist = maskA;
    for (int b = tid; b < NBINS; b += NTHR) hist[b] = 0u;
    __syncthreads();
    for (int e = tid; e < NPRED; e += NTHR) {
      const float4 q = *reinterpret_cast<const float4*>(base + (size_t)e * 8 + 4);
      float m = scoreOf(q);
      int b = (int)(m * (float)NBINS);
      b = min(max(b, 0), NBINS - 1);
      atomicAdd(&hist[b], 1u);
    }
    __syncthreads();
    const uint4 h = *reinterpret_cast<const uint4*>(hist + (tid << 2));
    h0 = h.x; h1 = h.y; h2 = h.z; h3 = h.w;
  }

  // ---- suffix scan of per-thread 4-bin sums (shfl within wave + 16 wave totals) ----
  unsigned g = h0 + h1 + h2 + h3;
  unsigned s = g;
#pragma unroll
  for (int d = 1; d < 64; d <<= 1) {
    unsigned o = __shfl_down(s, d, 64);
    if (lane + d < 64) s += o;
  }
  if (lane == 0) wtot[wid] = s;
  __syncthreads();
  if (tid < 16) {
    unsigned t = wtot[tid];
#pragma unroll
    for (int d = 1; d < 16; d <<= 1) {
      unsigned o = __shfl_down(t, d, 64);
      if (tid + d < 16) t += o;
    }
    wtot[tid] = t;
  }
  __syncthreads();
  unsigned S = s + ((wid < 15) ? wtot[wid + 1] : 0u);
  // unique thread: suffix(4t) >= K and suffix(4t+4) < K; walk its 4 bins downward
  if (S >= KTOP && (S - g) < KTOP) {
    unsigned acc = S - g;
    int cut;
    acc += h3;
    if (acc >= KTOP) cut = 4 * tid + 3;
    else {
      acc += h2;
      if (acc >= KTOP) cut = 4 * tid + 2;
      else {
        acc += h1;
        if (acc >= KTOP) cut = 4 * tid + 1;
        else cut = 4 * tid;
      }
    }
    cutoff_s = cut;
  }
  __syncthreads();
  const int cutoff = cutoff_s;

  // ---- phase B: collect candidates with bin >= cutoff (recompute scores) ----
  for (int e = tid; e < NPRED; e += NTHR) {
    const float4 q = *reinterpret_cast<const float4*>(base + (size_t)e * 8 + 4);
    float m = scoreOf(q);
    int b = (int)(m * (float)NBINS);
    b = min(max(b, 0), NBINS - 1);
    if (b >= cutoff) {
      int p = atomicAdd(&cnt_s, 1);
      if (p < CAP) {
        keysL[p] = (((unsigned long long)__float_as_uint(m)) << 32)
                 | (unsigned)(0x7FFFFFFF - e);
      }
    }
  }
  __syncthreads();
  const int cnt = min(cnt_s, CAP);
  unsigned long long key = (tid < cnt) ? keysL[tid] : 0ull;

  // ---- phase C: hybrid bitonic sort (desc by key); element stays in register ----
  for (int k = 2; k <= CAP; k <<= 1) {
    for (int j = k >> 1; j > 0; j >>= 1) {
      unsigned long long p;
      if (j >= 64) {
        __syncthreads();
        keysL[tid] = key;
        __syncthreads();
        p = keysL[tid ^ j];
      } else {
        p = shflx64(key, j);
      }
      bool lower = ((tid & j) == 0);
      bool descR = ((tid & k) == 0);
      bool takeMax = (lower == descR);
      bool pGreater = (p > key);
      key = (takeMax == pGreater) ? p : key;
    }
  }
  // thread tid now holds sorted[tid] in `key` (desc by value, asc by index)

  // ---- phase D: build boxes for top-K + zero-init mask ----
  if (tid < KTOP) {
    int gi = 0x7FFFFFFF - (int)(unsigned)(key & 0xffffffffull);
    if ((unsigned)gi >= NPRED) gi = 0;              // safety only (cnt>=KTOP by construction)
    float v = __uint_as_float((unsigned)(key >> 32));
    const float4 a = *reinterpret_cast<const float4*>(base + (size_t)gi * 8);
    const float4 q = *reinterpret_cast<const float4*>(base + (size_t)gi * 8 + 4);
    float p0 = q.x * q.y, p1 = q.x * q.z, p2 = q.x * q.w;
    float m = fmaxf(p0, fmaxf(p1, p2));
    int c = (p0 == m) ? 0 : ((p1 == m) ? 1 : 2);    // first-max == jnp.argmax
    float x0 = a.x - a.z * 0.5f;
    float y0 = a.y - a.w * 0.5f;
    float x1 = a.x + a.z * 0.5f;
    float y1 = a.y + a.w * 0.5f;
    float co = (float)c * MAXWH;
    bx0[tid] = x0; bx1[tid] = y0; bx2[tid] = x1; bx3[tid] = y1;
    float o0 = x0 + co, o1 = y0 + co, o2 = x1 + co, o3 = y1 + co;
    ox0[tid] = o0; oy0[tid] = o1; ox1[tid] = o2; oy1[tid] = o3;
    areaL[tid] = (o2 - o0) * (o3 - o1);
    cidL[tid] = c;
    svL[tid] = v; siL[tid] = gi;
  }
  for (int w = tid; w < KTOP * MSTRIDE; w += NTHR) maskA[w] = 0u;
  __syncthreads();

  // ---- phase E: suppression mask via ballot (lane owns j; i broadcast by shfl) ----
  {
    const int jb = wid & 7;          // j-block [64*jb, 64*jb+64)
    const int half = wid >> 3;       // even/odd i split between wave pairs
    const int j = (jb << 6) + lane;
    const float jx0 = ox0[j], jy0 = oy0[j], jx1 = ox1[j], jy1 = oy1[j], ja = areaL[j];
    const int iend = (jb << 6) + 63; // rows i < iend have some j > i in this block
    for (int ibase = 0; ibase < iend; ibase += 64) {
      float cx0 = ox0[ibase + lane], cy0 = oy0[ibase + lane];
      float cx1 = ox1[ibase + lane], cy1 = oy1[ibase + lane];
      float ca = areaL[ibase + lane];
      int bbend = min(64, iend - ibase);
      for (int bb = half; bb < bbend; bb += 2) {
        float ix0 = __shfl(cx0, bb, 64);
        float iy0 = __shfl(cy0, bb, 64);
        float ix1 = __shfl(cx1, bb, 64);
        float iy1 = __shfl(cy1, bb, 64);
        float ia  = __shfl(ca,  bb, 64);
        int i = ibase + bb;
        float xx0 = fmaxf(ix0, jx0);
        float yy0 = fmaxf(iy0, jy0);
        float xx1 = fminf(ix1, jx1);
        float yy1 = fminf(iy1, jy1);
        float iw = fmaxf(xx1 - xx0, 0.0f);
        float ih = fmaxf(yy1 - yy0, 0.0f);
        float inter = iw * ih;
        float denom = ia + ja - inter + 1e-7f;
        bool sup = (inter > IOU_T * denom) && (j > i);
        unsigned long long b = __ballot(sup);
        if (lane < 2) maskA[i * MSTRIDE + (jb << 1) + lane] = (unsigned)(b >> (lane << 5));
      }
    }
  }
  __syncthreads();

  // ---- phase F: greedy walk, register-chunked (16 lanes hold 512-bit state) ----
  if (tid < 16) {
    unsigned sst = 0u;
    for (int c = 0; c < KTOP / 16; ++c) {
      const int rb = c * 16;
      const int wi = rb >> 5;
      const int b0 = rb & 31;
      unsigned myrow[16], diag[16];
#pragma unroll
      for (int r = 0; r < 16; ++r) {
        myrow[r] = maskA[(rb + r) * MSTRIDE + tid];
        diag[r]  = maskA[(rb + r) * MSTRIDE + wi];
      }
      unsigned wcur = __shfl(sst, wi, 64);
#pragma unroll
      for (int r = 0; r < 16; ++r) {
        if (!((wcur >> (b0 + r)) & 1u)) { sst |= myrow[r]; wcur |= diag[r]; }
      }
    }
    supW[tid] = sst;
  }
  __syncthreads();

  // ---- phase G: rank/valid via ballot scans + stable partition pack ----
  bool keep = false;
  float score = 0.0f;
  if (tid < KTOP) {
    keep = !((supW[tid >> 5] >> (tid & 31)) & 1u);
    score = svL[tid];
  }
  unsigned long long balK = __ballot(keep);
  int wpre = __popcll(balK & ((1ull << lane) - 1ull));
  if (lane == 63 && wid < 8) wtot[wid] = (unsigned)(wpre + (keep ? 1 : 0));
  __syncthreads();
  if (tid == 0) {
    int a = 0;
    for (int w = 0; w < 8; ++w) { woff[w] = a; a += (int)wtot[w]; }
  }
  __syncthreads();
  bool valid = false;
  if (tid < KTOP) {
    int rank = woff[wid] + wpre + (keep ? 1 : 0);
    valid = keep && ((score > CONF_T) || (rank <= 1));  // MIN_DET = 1
  }
  __syncthreads();
  unsigned long long balV = __ballot(valid);
  int vpre = __popcll(balV & ((1ull << lane) - 1ull));
  if (lane == 63 && wid < 8) wtot[wid] = (unsigned)(vpre + (valid ? 1 : 0));
  __syncthreads();
  if (tid == 0) {
    int a = 0;
    for (int w = 0; w < 8; ++w) { woff[w] = a; a += (int)wtot[w]; }
    nvalid_s = a;
  }
  __syncthreads();
  if (tid < KTOP) {
    int vs = woff[wid] + vpre + (valid ? 1 : 0);
    int nvalid = nvalid_s;
    int pos = valid ? (vs - 1) : (nvalid + tid - vs);
    if (pos < MAXDET) {
      const int SB = BS * MAXDET;
      float* outBoxes  = out;                    // [BS][300][4]
      float* outScores = out + (size_t)SB * 4;   // [BS][300]
      float* outCls    = outScores + SB;
      float* outIds    = outCls + SB;
      float* outValid  = outIds + SB;
      size_t row = (size_t)img * MAXDET + pos;
      if (valid) {
        outBoxes[row * 4 + 0] = bx0[tid];
        outBoxes[row * 4 + 1] = bx1[tid];
        outBoxes[row * 4 + 2] = bx2[tid];
        outBoxes[row * 4 + 3] = bx3[tid];
        outScores[row] = score;
      } else {
        outBoxes[row * 4 + 0] = 0.0f;
        outBoxes[row * 4 + 1] = 0.0f;
        outBoxes[row * 4 + 2] = 0.0f;
        outBoxes[row * 4 + 3] = 0.0f;
        outScores[row] = 0.0f;
      }
      outCls[row]   = (float)cidL[tid];          // not masked (matches reference)
      outIds[row]   = (float)(siL[tid] / 3);     // topi // ANCHORS_PER_CELL
      outValid[row] = valid ? 1.0f : 0.0f;
    }
  }
}

extern "C" void kernel_launch(void* const* d_in, const int* in_sizes, int n_in,
                              void* d_out, int out_size, void* d_ws, size_t ws_size,
                              hipStream_t stream) {
  (void)in_sizes; (void)n_in; (void)out_size;
  const float* pred = (const float*)d_in[0];
  float* out = (float*)d_out;
  const size_t need = (size_t)BS * NBINS * sizeof(unsigned int);  // 1 MB
  if (d_ws != nullptr && ws_size >= need) {
    unsigned int* ghist = (unsigned int*)d_ws;
    hipMemsetAsync(d_ws, 0, need, stream);
    score_hist_k<<<dim3((NPRED + 255) / 256, BS), 256, 0, stream>>>(pred, ghist);
    nms_k<true><<<BS, NTHR, 0, stream>>>(pred, ghist, out);
  } else {
    nms_k<false><<<BS, NTHR, 0, stream>>>(pred, nullptr, out);
  }
}

// Round 6
// 161.628 us; speedup vs baseline: 1.4921x; 1.4921x over previous
//
#include <hip/hip_runtime.h>
#include <cstdint>
#include <cstddef>

#define BS      64
#define NPRED   25200
#define KTOP    512
#define MAXDET  300
#define NBINS   4096
#define CAP     1024
#define NTHR    1024
#define CONF_T  0.25f
#define IOU_T   0.45f
#define MAXWH   7680.0f
#define MSTRIDE 17
#define NVEC    3150   // NPRED/8 : uint4 vectors of u16 bins per image

__device__ __forceinline__ unsigned long long shflx64(unsigned long long v, int m) {
  unsigned lo = __shfl_xor((unsigned)(v & 0xffffffffull), m, 64);
  unsigned hi = __shfl_xor((unsigned)(v >> 32), m, 64);
  return (((unsigned long long)hi) << 32) | lo;
}

__device__ __forceinline__ float scoreOf(const float4& q) {
  return fmaxf(q.x * q.y, fmaxf(q.x * q.z, q.x * q.w));
}

// ---- K1: full-grid score->bin precompute (NO atomics; full HBM BW) ----
__global__ __launch_bounds__(256) void bin_k(const float* __restrict__ pred,
                                             unsigned short* __restrict__ bins) {
  const int t = blockIdx.x * 256 + threadIdx.x;
  const int e0 = t * 2;
  if (e0 >= BS * NPRED) return;
  const float4 q0 = *reinterpret_cast<const float4*>(pred + (size_t)e0 * 8 + 4);
  const float4 q1 = *reinterpret_cast<const float4*>(pred + (size_t)e0 * 8 + 12);
  int b0 = min(max((int)(scoreOf(q0) * (float)NBINS), 0), NBINS - 1);
  int b1 = min(max((int)(scoreOf(q1) * (float)NBINS), 0), NBINS - 1);
  *reinterpret_cast<unsigned int*>(bins + e0) = (unsigned)b0 | ((unsigned)b1 << 16);
}

// ---- K2: per-image top-K select/sort + NMS + pack ----
// BINS=true: candidate scan reads precomputed u16 bins (50 KB/img) from ws.
// BINS=false: self-contained fallback (scans pred directly).
template<bool BINS>
__global__ __launch_bounds__(NTHR) void nms_k(const float* __restrict__ pred,
                                              const unsigned short* __restrict__ bins,
                                              float* __restrict__ out) {
  __shared__ unsigned long long keysL[CAP];                    // 8 KB
  __shared__ __align__(16) unsigned int maskA[KTOP * MSTRIDE]; // 34.8 KB (hist+eList overlay)
  __shared__ float ox0[KTOP], oy0[KTOP], ox1[KTOP], oy1[KTOP], areaL[KTOP];
  __shared__ float bx0[KTOP], bx1[KTOP], bx2[KTOP], bx3[KTOP];
  __shared__ float svL[KTOP]; __shared__ int siL[KTOP]; __shared__ int cidL[KTOP];
  __shared__ unsigned int supW[16];
  __shared__ unsigned int wtot[16];
  __shared__ int woff[8];
  __shared__ int cutoff_s, cnt_s, nvalid_s;

  unsigned int* hist = maskA;                 // [0, 4096) uints
  int* eList = (int*)(maskA + NBINS);         // [4096, 5120) uints (BINS path only)

  const int tid = threadIdx.x;
  const int lane = tid & 63;
  const int wid = tid >> 6;
  const int img = blockIdx.x;
  const float* __restrict__ base = pred + (size_t)img * (NPRED * 8);
  const unsigned short* __restrict__ bimg = BINS ? (bins + (size_t)img * NPRED) : nullptr;

  if (tid == 0) cnt_s = 0;

  // ---- phase A: build LDS histogram ----
  for (int b = tid; b < NBINS; b += NTHR) hist[b] = 0u;
  __syncthreads();
  if constexpr (BINS) {
    for (int v = tid; v < NVEC; v += NTHR) {
      const uint4 u = *reinterpret_cast<const uint4*>(bimg + (size_t)v * 8);
      atomicAdd(&hist[u.x & 0xffffu], 1u); atomicAdd(&hist[u.x >> 16], 1u);
      atomicAdd(&hist[u.y & 0xffffu], 1u); atomicAdd(&hist[u.y >> 16], 1u);
      atomicAdd(&hist[u.z & 0xffffu], 1u); atomicAdd(&hist[u.z >> 16], 1u);
      atomicAdd(&hist[u.w & 0xffffu], 1u); atomicAdd(&hist[u.w >> 16], 1u);
    }
  } else {
    for (int e = tid; e < NPRED; e += NTHR) {
      const float4 q = *reinterpret_cast<const float4*>(base + (size_t)e * 8 + 4);
      float m = scoreOf(q);
      int b = (int)(m * (float)NBINS);
      b = min(max(b, 0), NBINS - 1);
      atomicAdd(&hist[b], 1u);
    }
  }
  __syncthreads();
  const uint4 h = *reinterpret_cast<const uint4*>(hist + (tid << 2));
  unsigned h0 = h.x, h1 = h.y, h2 = h.z, h3 = h.w;

  // ---- suffix scan of per-thread 4-bin sums -> cutoff bin ----
  unsigned g = h0 + h1 + h2 + h3;
  unsigned s = g;
#pragma unroll
  for (int d = 1; d < 64; d <<= 1) {
    unsigned o = __shfl_down(s, d, 64);
    if (lane + d < 64) s += o;
  }
  if (lane == 0) wtot[wid] = s;
  __syncthreads();
  if (tid < 16) {
    unsigned t = wtot[tid];
#pragma unroll
    for (int d = 1; d < 16; d <<= 1) {
      unsigned o = __shfl_down(t, d, 64);
      if (tid + d < 16) t += o;
    }
    wtot[tid] = t;
  }
  __syncthreads();
  unsigned S = s + ((wid < 15) ? wtot[wid + 1] : 0u);
  if (S >= KTOP && (S - g) < KTOP) {   // unique thread
    unsigned acc = S - g;
    int cut;
    acc += h3;
    if (acc >= KTOP) cut = 4 * tid + 3;
    else {
      acc += h2;
      if (acc >= KTOP) cut = 4 * tid + 2;
      else {
        acc += h1;
        if (acc >= KTOP) cut = 4 * tid + 1;
        else cut = 4 * tid;
      }
    }
    cutoff_s = cut;
  }
  __syncthreads();
  const int cutoff = cutoff_s;

  // ---- phase B: collect candidates (bin >= cutoff) + build sort keys ----
  unsigned long long key = 0ull;
  if constexpr (BINS) {
    for (int v = tid; v < NVEC; v += NTHR) {
      const uint4 u = *reinterpret_cast<const uint4*>(bimg + (size_t)v * 8);
      const int e0 = v * 8;
      unsigned bb[8] = { u.x & 0xffffu, u.x >> 16, u.y & 0xffffu, u.y >> 16,
                         u.z & 0xffffu, u.z >> 16, u.w & 0xffffu, u.w >> 16 };
#pragma unroll
      for (int k = 0; k < 8; ++k) {
        if ((int)bb[k] >= cutoff) {
          int p = atomicAdd(&cnt_s, 1);
          if (p < CAP) eList[p] = e0 + k;
        }
      }
    }
    __syncthreads();
    const int cnt = min(cnt_s, CAP);
    if (tid < cnt) {     // one batched gather of exact scores for candidates
      int e = eList[tid];
      const float4 q = *reinterpret_cast<const float4*>(base + (size_t)e * 8 + 4);
      float m = scoreOf(q);
      key = (((unsigned long long)__float_as_uint(m)) << 32)
          | (unsigned)(0x7FFFFFFF - e);
    }
  } else {
    for (int e = tid; e < NPRED; e += NTHR) {
      const float4 q = *reinterpret_cast<const float4*>(base + (size_t)e * 8 + 4);
      float m = scoreOf(q);
      int b = (int)(m * (float)NBINS);
      b = min(max(b, 0), NBINS - 1);
      if (b >= cutoff) {
        int p = atomicAdd(&cnt_s, 1);
        if (p < CAP) {
          keysL[p] = (((unsigned long long)__float_as_uint(m)) << 32)
                   | (unsigned)(0x7FFFFFFF - e);
        }
      }
    }
    __syncthreads();
    const int cnt = min(cnt_s, CAP);
    key = (tid < cnt) ? keysL[tid] : 0ull;
  }

  // ---- phase C: hybrid bitonic sort (desc); element stays in register ----
  for (int k = 2; k <= CAP; k <<= 1) {
    for (int j = k >> 1; j > 0; j >>= 1) {
      unsigned long long p;
      if (j >= 64) {
        __syncthreads();
        keysL[tid] = key;
        __syncthreads();
        p = keysL[tid ^ j];
      } else {
        p = shflx64(key, j);
      }
      bool lower = ((tid & j) == 0);
      bool descR = ((tid & k) == 0);
      bool takeMax = (lower == descR);
      bool pGreater = (p > key);
      key = (takeMax == pGreater) ? p : key;
    }
  }
  // thread tid holds sorted[tid] (desc by value, asc by index)

  // ---- phase D: build boxes for top-K + zero-init mask ----
  if (tid < KTOP) {
    int gi = 0x7FFFFFFF - (int)(unsigned)(key & 0xffffffffull);
    if ((unsigned)gi >= NPRED) gi = 0;              // safety only
    float v = __uint_as_float((unsigned)(key >> 32));
    const float4 a = *reinterpret_cast<const float4*>(base + (size_t)gi * 8);
    const float4 q = *reinterpret_cast<const float4*>(base + (size_t)gi * 8 + 4);
    float p0 = q.x * q.y, p1 = q.x * q.z, p2 = q.x * q.w;
    float m = fmaxf(p0, fmaxf(p1, p2));
    int c = (p0 == m) ? 0 : ((p1 == m) ? 1 : 2);    // first-max == jnp.argmax
    float x0 = a.x - a.z * 0.5f;
    float y0 = a.y - a.w * 0.5f;
    float x1 = a.x + a.z * 0.5f;
    float y1 = a.y + a.w * 0.5f;
    float co = (float)c * MAXWH;
    bx0[tid] = x0; bx1[tid] = y0; bx2[tid] = x1; bx3[tid] = y1;
    float o0 = x0 + co, o1 = y0 + co, o2 = x1 + co, o3 = y1 + co;
    ox0[tid] = o0; oy0[tid] = o1; ox1[tid] = o2; oy1[tid] = o3;
    areaL[tid] = (o2 - o0) * (o3 - o1);
    cidL[tid] = c;
    svL[tid] = v; siL[tid] = gi;
  }
  __syncthreads();   // eList/hist dead; safe to re-init maskA
  for (int w = tid; w < KTOP * MSTRIDE; w += NTHR) maskA[w] = 0u;
  __syncthreads();

  // ---- phase E: suppression mask via ballot (lane owns j; i broadcast) ----
  {
    const int jb = wid & 7;
    const int half = wid >> 3;
    const int j = (jb << 6) + lane;
    const float jx0 = ox0[j], jy0 = oy0[j], jx1 = ox1[j], jy1 = oy1[j], ja = areaL[j];
    const int iend = (jb << 6) + 63;
    for (int ibase = 0; ibase < iend; ibase += 64) {
      float cx0 = ox0[ibase + lane], cy0 = oy0[ibase + lane];
      float cx1 = ox1[ibase + lane], cy1 = oy1[ibase + lane];
      float ca = areaL[ibase + lane];
      int bbend = min(64, iend - ibase);
      for (int bb = half; bb < bbend; bb += 2) {
        float ix0 = __shfl(cx0, bb, 64);
        float iy0 = __shfl(cy0, bb, 64);
        float ix1 = __shfl(cx1, bb, 64);
        float iy1 = __shfl(cy1, bb, 64);
        float ia  = __shfl(ca,  bb, 64);
        int i = ibase + bb;
        float xx0 = fmaxf(ix0, jx0);
        float yy0 = fmaxf(iy0, jy0);
        float xx1 = fminf(ix1, jx1);
        float yy1 = fminf(iy1, jy1);
        float iw = fmaxf(xx1 - xx0, 0.0f);
        float ih = fmaxf(yy1 - yy0, 0.0f);
        float inter = iw * ih;
        float denom = ia + ja - inter + 1e-7f;
        bool sup = (inter > IOU_T * denom) && (j > i);
        unsigned long long b = __ballot(sup);
        if (lane < 2) maskA[i * MSTRIDE + (jb << 1) + lane] = (unsigned)(b >> (lane << 5));
      }
    }
  }
  __syncthreads();

  // ---- phase F: greedy walk, register-chunked (16 lanes, 512-bit state) ----
  if (tid < 16) {
    unsigned sst = 0u;
    for (int c = 0; c < KTOP / 16; ++c) {
      const int rb = c * 16;
      const int wi = rb >> 5;
      const int b0 = rb & 31;
      unsigned myrow[16], diag[16];
#pragma unroll
      for (int r = 0; r < 16; ++r) {
        myrow[r] = maskA[(rb + r) * MSTRIDE + tid];
        diag[r]  = maskA[(rb + r) * MSTRIDE + wi];
      }
      unsigned wcur = __shfl(sst, wi, 64);
#pragma unroll
      for (int r = 0; r < 16; ++r) {
        if (!((wcur >> (b0 + r)) & 1u)) { sst |= myrow[r]; wcur |= diag[r]; }
      }
    }
    supW[tid] = sst;
  }
  __syncthreads();

  // ---- phase G: rank/valid via ballot scans + stable partition pack ----
  bool keep = false;
  float score = 0.0f;
  if (tid < KTOP) {
    keep = !((supW[tid >> 5] >> (tid & 31)) & 1u);
    score = svL[tid];
  }
  unsigned long long balK = __ballot(keep);
  int wpre = __popcll(balK & ((1ull << lane) - 1ull));
  if (lane == 63 && wid < 8) wtot[wid] = (unsigned)(wpre + (keep ? 1 : 0));
  __syncthreads();
  if (tid == 0) {
    int a = 0;
    for (int w = 0; w < 8; ++w) { woff[w] = a; a += (int)wtot[w]; }
  }
  __syncthreads();
  bool valid = false;
  if (tid < KTOP) {
    int rank = woff[wid] + wpre + (keep ? 1 : 0);
    valid = keep && ((score > CONF_T) || (rank <= 1));  // MIN_DET = 1
  }
  __syncthreads();
  unsigned long long balV = __ballot(valid);
  int vpre = __popcll(balV & ((1ull << lane) - 1ull));
  if (lane == 63 && wid < 8) wtot[wid] = (unsigned)(vpre + (valid ? 1 : 0));
  __syncthreads();
  if (tid == 0) {
    int a = 0;
    for (int w = 0; w < 8; ++w) { woff[w] = a; a += (int)wtot[w]; }
    nvalid_s = a;
  }
  __syncthreads();
  if (tid < KTOP) {
    int vs = woff[wid] + vpre + (valid ? 1 : 0);
    int nvalid = nvalid_s;
    int pos = valid ? (vs - 1) : (nvalid + tid - vs);
    if (pos < MAXDET) {
      const int SB = BS * MAXDET;
      float* outBoxes  = out;                    // [BS][300][4]
      float* outScores = out + (size_t)SB * 4;   // [BS][300]
      float* outCls    = outScores + SB;
      float* outIds    = outCls + SB;
      float* outValid  = outIds + SB;
      size_t row = (size_t)img * MAXDET + pos;
      if (valid) {
        outBoxes[row * 4 + 0] = bx0[tid];
        outBoxes[row * 4 + 1] = bx1[tid];
        outBoxes[row * 4 + 2] = bx2[tid];
        outBoxes[row * 4 + 3] = bx3[tid];
        outScores[row] = score;
      } else {
        outBoxes[row * 4 + 0] = 0.0f;
        outBoxes[row * 4 + 1] = 0.0f;
        outBoxes[row * 4 + 2] = 0.0f;
        outBoxes[row * 4 + 3] = 0.0f;
        outScores[row] = 0.0f;
      }
      outCls[row]   = (float)cidL[tid];          // not masked (matches reference)
      outIds[row]   = (float)(siL[tid] / 3);     // topi // ANCHORS_PER_CELL
      outValid[row] = valid ? 1.0f : 0.0f;
    }
  }
}

extern "C" void kernel_launch(void* const* d_in, const int* in_sizes, int n_in,
                              void* d_out, int out_size, void* d_ws, size_t ws_size,
                              hipStream_t stream) {
  (void)in_sizes; (void)n_in; (void)out_size;
  const float* pred = (const float*)d_in[0];
  float* out = (float*)d_out;
  const size_t need = (size_t)BS * NPRED * sizeof(unsigned short);  // 3.2 MB
  if (d_ws != nullptr && ws_size >= need) {
    unsigned short* bins = (unsigned short*)d_ws;
    bin_k<<<(BS * NPRED / 2 + 255) / 256, 256, 0, stream>>>(pred, bins);
    nms_k<true><<<BS, NTHR, 0, stream>>>(pred, bins, out);
  } else {
    nms_k<false><<<BS, NTHR, 0, stream>>>(pred, nullptr, out);
  }
}

// Round 7
// 134.500 us; speedup vs baseline: 1.7930x; 1.2017x over previous
//
#include <hip/hip_runtime.h>
#include <cstdint>
#include <cstddef>

#define BS      64
#define NPRED   25200
#define KTOP    512
#define MAXDET  300
#define NBINS   4096
#define CAP     1024
#define NTHR    1024
#define CONF_T  0.25f
#define IOU_T   0.45f
#define MAXWH   7680.0f
#define MSTRIDE 18     // words per mask row (16 data + 2 pad; even -> 8B-aligned rows)
#define NITER   25     // ceil(NPRED / NTHR)

__device__ __forceinline__ unsigned long long shflx64(unsigned long long v, int m) {
  unsigned lo = __shfl_xor((unsigned)(v & 0xffffffffull), m, 64);
  unsigned hi = __shfl_xor((unsigned)(v >> 32), m, 64);
  return (((unsigned long long)hi) << 32) | lo;
}

__device__ __forceinline__ float scoreOf(const float4& q) {
  return fmaxf(q.x * q.y, fmaxf(q.x * q.z, q.x * q.w));
}

// Single fused kernel, one block per image. No d_ws usage.
__global__ __launch_bounds__(NTHR) void yolo_k(const float* __restrict__ pred,
                                               float* __restrict__ out) {
  __shared__ unsigned long long keysL[CAP];                      // 8 KB
  __shared__ __align__(16) unsigned int maskA[KTOP * MSTRIDE];   // 36.9 KB (hist overlay)
  __shared__ float ox0[KTOP], oy0[KTOP], ox1[KTOP], oy1[KTOP], areaL[KTOP];
  __shared__ float bx0[KTOP], bx1[KTOP], bx2[KTOP], bx3[KTOP];
  __shared__ float svL[KTOP]; __shared__ int siL[KTOP]; __shared__ int cidL[KTOP];
  __shared__ unsigned int supW[16];
  __shared__ unsigned int wtot[16];
  __shared__ int woff[8];
  __shared__ int cutoff_s, cnt_s, nvalid_s;

  unsigned int* hist = maskA;   // first 4096 words (dead before maskA zero-init)

  const int tid = threadIdx.x;
  const int lane = tid & 63;
  const int wid = tid >> 6;
  const int img = blockIdx.x;
  const float* __restrict__ base = pred + (size_t)img * (NPRED * 8);

  if (tid == 0) cnt_s = 0;

  // ---- phase A: score all anchors; cache in registers; LDS histogram ----
  for (int b = tid; b < NBINS; b += NTHR) hist[b] = 0u;
  __syncthreads();
  float sc[NITER];
#pragma unroll
  for (int it = 0; it < NITER; ++it) {
    const int e = tid + (it << 10);
    float m = -1.0f;
    if (e < NPRED) {
      const float4 q = *reinterpret_cast<const float4*>(base + (size_t)e * 8 + 4);
      m = scoreOf(q);
      int b = (int)(m * (float)NBINS);
      b = min(max(b, 0), NBINS - 1);
      atomicAdd(&hist[b], 1u);
    }
    sc[it] = m;
  }
  __syncthreads();
  const uint4 h = *reinterpret_cast<const uint4*>(hist + (tid << 2));
  const unsigned h0 = h.x, h1 = h.y, h2 = h.z, h3 = h.w;

  // ---- suffix scan of per-thread 4-bin sums -> cutoff bin ----
  unsigned g = h0 + h1 + h2 + h3;
  unsigned s = g;
#pragma unroll
  for (int d = 1; d < 64; d <<= 1) {
    unsigned o = __shfl_down(s, d, 64);
    if (lane + d < 64) s += o;
  }
  if (lane == 0) wtot[wid] = s;
  __syncthreads();
  if (tid < 16) {
    unsigned t = wtot[tid];
#pragma unroll
    for (int d = 1; d < 16; d <<= 1) {
      unsigned o = __shfl_down(t, d, 64);
      if (tid + d < 16) t += o;
    }
    wtot[tid] = t;
  }
  __syncthreads();
  unsigned S = s + ((wid < 15) ? wtot[wid + 1] : 0u);
  if (S >= KTOP && (S - g) < KTOP) {   // exactly one thread
    unsigned acc = S - g;
    int cut;
    acc += h3;
    if (acc >= KTOP) cut = 4 * tid + 3;
    else {
      acc += h2;
      if (acc >= KTOP) cut = 4 * tid + 2;
      else {
        acc += h1;
        if (acc >= KTOP) cut = 4 * tid + 1;
        else cut = 4 * tid;
      }
    }
    cutoff_s = cut;
  }
  __syncthreads();
  const int cutoff = cutoff_s;

  // ---- phase B: collect candidates (bin >= cutoff) from registers ----
#pragma unroll
  for (int it = 0; it < NITER; ++it) {
    const int e = tid + (it << 10);
    if (e < NPRED) {
      float m = sc[it];
      int b = (int)(m * (float)NBINS);
      b = min(max(b, 0), NBINS - 1);
      if (b >= cutoff) {
        int p = atomicAdd(&cnt_s, 1);
        if (p < CAP) {
          keysL[p] = (((unsigned long long)__float_as_uint(m)) << 32)
                   | (unsigned)(0x7FFFFFFF - e);
        }
      }
    }
  }
  __syncthreads();
  const int cnt = min(cnt_s, CAP);
  unsigned long long key = (tid < cnt) ? keysL[tid] : 0ull;

  // ---- phase C: hybrid bitonic sort (desc); element stays in register ----
  for (int k = 2; k <= CAP; k <<= 1) {
    for (int j = k >> 1; j > 0; j >>= 1) {
      unsigned long long p;
      if (j >= 64) {
        __syncthreads();
        keysL[tid] = key;
        __syncthreads();
        p = keysL[tid ^ j];
      } else {
        p = shflx64(key, j);
      }
      bool lower = ((tid & j) == 0);
      bool descR = ((tid & k) == 0);
      bool takeMax = (lower == descR);
      bool pGreater = (p > key);
      key = (takeMax == pGreater) ? p : key;
    }
  }
  // thread tid holds sorted[tid] (desc by value, asc by index)

  // ---- phase D: build boxes for top-K + zero-init mask ----
  if (tid < KTOP) {
    int gi = 0x7FFFFFFF - (int)(unsigned)(key & 0xffffffffull);
    if ((unsigned)gi >= NPRED) gi = 0;              // safety only
    float v = __uint_as_float((unsigned)(key >> 32));
    const float4 a = *reinterpret_cast<const float4*>(base + (size_t)gi * 8);
    const float4 q = *reinterpret_cast<const float4*>(base + (size_t)gi * 8 + 4);
    float p0 = q.x * q.y, p1 = q.x * q.z, p2 = q.x * q.w;
    float m = fmaxf(p0, fmaxf(p1, p2));
    int c = (p0 == m) ? 0 : ((p1 == m) ? 1 : 2);    // first-max == jnp.argmax
    float x0 = a.x - a.z * 0.5f;
    float y0 = a.y - a.w * 0.5f;
    float x1 = a.x + a.z * 0.5f;
    float y1 = a.y + a.w * 0.5f;
    float co = (float)c * MAXWH;
    bx0[tid] = x0; bx1[tid] = y0; bx2[tid] = x1; bx3[tid] = y1;
    float o0 = x0 + co, o1 = y0 + co, o2 = x1 + co, o3 = y1 + co;
    ox0[tid] = o0; oy0[tid] = o1; ox1[tid] = o2; oy1[tid] = o3;
    areaL[tid] = (o2 - o0) * (o3 - o1);
    cidL[tid] = c;
    svL[tid] = v; siL[tid] = gi;
  }
  __syncthreads();   // hist dead; safe to re-init maskA
  for (int w = tid; w < KTOP * MSTRIDE; w += NTHR) maskA[w] = 0u;
  __syncthreads();

  // ---- phase E: balanced suppression-mask build ----
  // Wave w handles rows i = w, w+16, ... (exactly 144 (i,jb) units per wave).
  // Lane owns j = 64*jb + lane; i-box via uniform broadcast reads; one 64-bit
  // ballot store per unit; diagonal handled by per-lane (j > i).
  {
    for (int jb = 0; jb < 8; ++jb) {
      const int j = (jb << 6) + lane;
      const float jx0 = ox0[j], jy0 = oy0[j], jx1 = ox1[j], jy1 = oy1[j];
      const float ja = areaL[j];
      const int ilim = (jb + 1) << 6;
      for (int i = wid; i < ilim; i += 16) {
        const float ix0 = ox0[i], iy0 = oy0[i], ix1 = ox1[i], iy1 = oy1[i];
        const float ia = areaL[i];
        float xx0 = fmaxf(ix0, jx0);
        float yy0 = fmaxf(iy0, jy0);
        float xx1 = fminf(ix1, jx1);
        float yy1 = fminf(iy1, jy1);
        float iw = fmaxf(xx1 - xx0, 0.0f);
        float ih = fmaxf(yy1 - yy0, 0.0f);
        float inter = iw * ih;
        float denom = ia + ja - inter + 1e-7f;
        bool sup = (inter > IOU_T * denom) && (j > i);
        unsigned long long bal = __ballot(sup);
        if (lane == 0) {
          *reinterpret_cast<unsigned long long*>(maskA + i * MSTRIDE + (jb << 1)) = bal;
        }
      }
    }
  }
  __syncthreads();

  // ---- phase F: greedy walk, register-chunked (16 lanes, 512-bit state) ----
  if (tid < 16) {
    unsigned sst = 0u;
    for (int c = 0; c < KTOP / 16; ++c) {
      const int rb = c * 16;
      const int wi = rb >> 5;
      const int b0 = rb & 31;
      unsigned myrow[16], diag[16];
#pragma unroll
      for (int r = 0; r < 16; ++r) {
        myrow[r] = maskA[(rb + r) * MSTRIDE + tid];
        diag[r]  = maskA[(rb + r) * MSTRIDE + wi];
      }
      unsigned wcur = __shfl(sst, wi, 64);
#pragma unroll
      for (int r = 0; r < 16; ++r) {
        if (!((wcur >> (b0 + r)) & 1u)) { sst |= myrow[r]; wcur |= diag[r]; }
      }
    }
    supW[tid] = sst;
  }
  __syncthreads();

  // ---- phase G: rank/valid via ballot scans + stable partition pack ----
  bool keep = false;
  float score = 0.0f;
  if (tid < KTOP) {
    keep = !((supW[tid >> 5] >> (tid & 31)) & 1u);
    score = svL[tid];
  }
  unsigned long long balK = __ballot(keep);
  int wpre = __popcll(balK & ((1ull << lane) - 1ull));
  if (lane == 63 && wid < 8) wtot[wid] = (unsigned)(wpre + (keep ? 1 : 0));
  __syncthreads();
  if (tid == 0) {
    int a = 0;
    for (int w = 0; w < 8; ++w) { woff[w] = a; a += (int)wtot[w]; }
  }
  __syncthreads();
  bool valid = false;
  if (tid < KTOP) {
    int rank = woff[wid] + wpre + (keep ? 1 : 0);
    valid = keep && ((score > CONF_T) || (rank <= 1));  // MIN_DET = 1
  }
  __syncthreads();
  unsigned long long balV = __ballot(valid);
  int vpre = __popcll(balV & ((1ull << lane) - 1ull));
  if (lane == 63 && wid < 8) wtot[wid] = (unsigned)(vpre + (valid ? 1 : 0));
  __syncthreads();
  if (tid == 0) {
    int a = 0;
    for (int w = 0; w < 8; ++w) { woff[w] = a; a += (int)wtot[w]; }
    nvalid_s = a;
  }
  __syncthreads();
  if (tid < KTOP) {
    int vs = woff[wid] + vpre + (valid ? 1 : 0);
    int nvalid = nvalid_s;
    int pos = valid ? (vs - 1) : (nvalid + tid - vs);
    if (pos < MAXDET) {
      const int SB = BS * MAXDET;
      float* outBoxes  = out;                    // [BS][300][4]
      float* outScores = out + (size_t)SB * 4;   // [BS][300]
      float* outCls    = outScores + SB;
      float* outIds    = outCls + SB;
      float* outValid  = outIds + SB;
      size_t row = (size_t)img * MAXDET + pos;
      if (valid) {
        outBoxes[row * 4 + 0] = bx0[tid];
        outBoxes[row * 4 + 1] = bx1[tid];
        outBoxes[row * 4 + 2] = bx2[tid];
        outBoxes[row * 4 + 3] = bx3[tid];
        outScores[row] = score;
      } else {
        outBoxes[row * 4 + 0] = 0.0f;
        outBoxes[row * 4 + 1] = 0.0f;
        outBoxes[row * 4 + 2] = 0.0f;
        outBoxes[row * 4 + 3] = 0.0f;
        outScores[row] = 0.0f;
      }
      outCls[row]   = (float)cidL[tid];          // not masked (matches reference)
      outIds[row]   = (float)(siL[tid] / 3);     // topi // ANCHORS_PER_CELL
      outValid[row] = valid ? 1.0f : 0.0f;
    }
  }
}

extern "C" void kernel_launch(void* const* d_in, const int* in_sizes, int n_in,
                              void* d_out, int out_size, void* d_ws, size_t ws_size,
                              hipStream_t stream) {
  (void)in_sizes; (void)n_in; (void)out_size; (void)d_ws; (void)ws_size;
  const float* pred = (const float*)d_in[0];
  float* out = (float*)d_out;
  yolo_k<<<BS, NTHR, 0, stream>>>(pred, out);
}